// Round 4
// baseline (153.162 us; speedup 1.0000x reference)
//
#include <hip/hip_runtime.h>
#include <cstdint>
#include <cstddef>

#define NN 4096
#define FDIM 256

typedef __attribute__((ext_vector_type(4))) float fx4;
typedef __attribute__((ext_vector_type(8))) short s8v;

__device__ inline uint16_t f2bf(float f) {
    union { float f; uint32_t u; } v; v.f = f;
    const uint32_t u = v.u;
    return (uint16_t)((u + 0x7FFFu + ((u >> 16) & 1u)) >> 16);
}

// ---------------- k_h: h = x @ W.T + b (kept in regs/LDS only) ----------------
// Outputs: gt = bf16(h) transposed [f][j] LINEAR (reg-loaded B-operand now),
// a1p/a2p = per-f-chunk partials of h@att_w1 / h@att_w2. h never hits HBM.
// 64x64 tile, 512 thr, dbuf + reg prefetch, intra-block K-split. 69.6KB -> 2/CU.
__global__ __launch_bounds__(512, 4) void k_h(const float* __restrict__ x,
        const float* __restrict__ W, const float* __restrict__ bias,
        const float* __restrict__ att_w, uint16_t* __restrict__ gt,
        float* __restrict__ a1p, float* __restrict__ a2p) {
    __shared__ __align__(16) float xs[2][64 * 68];
    __shared__ __align__(16) float wt[2][64 * 68];
    const int bi = blockIdx.x, bf = blockIdx.y;
    const int t = threadIdx.x;
    const int t256 = t & 255;
    const int kh = t >> 8;                         // K-half: 0 or 1
    const int tx = t256 & 15, ty = t256 >> 4;      // f-group, i-group
    float acc[4][4] = {};
    float rx[8], rw[8];
    #pragma unroll
    for (int u = 0; u < 8; ++u) {
        const int e = t + 512 * u, r = e >> 6, c = e & 63;
        rx[u] = x[(size_t)(bi * 64 + r) * 256 + c];
        rw[u] = W[(size_t)(bf * 64 + r) * 256 + c];
    }
    for (int p = 0; p < 4; ++p) {
        float* xb = xs[p & 1];
        float* wb = wt[p & 1];
        #pragma unroll
        for (int u = 0; u < 8; ++u) {
            const int e = t + 512 * u, r = e >> 6, c = e & 63;
            const int sw = 8 * ((c & 7) ^ ((c >> 3) & 7));
            xb[c * 68 + (r ^ sw)] = rx[u];
            wb[c * 68 + (r ^ sw)] = rw[u];
        }
        __syncthreads();
        if (p < 3) {
            const int kc = (p + 1) * 64;
            #pragma unroll
            for (int u = 0; u < 8; ++u) {
                const int e = t + 512 * u, r = e >> 6, c = e & 63;
                rx[u] = x[(size_t)(bi * 64 + r) * 256 + kc + c];
                rw[u] = W[(size_t)(bf * 64 + r) * 256 + kc + c];
            }
        }
        #pragma unroll 8
        for (int k = 0; k < 32; ++k) {
            const int kk = kh * 32 + k;
            const int sw = 8 * ((kk & 7) ^ ((kk >> 3) & 7));
            const fx4 av = *(const fx4*)(xb + kk * 68 + ((ty * 4) ^ sw));
            const fx4 bv = *(const fx4*)(wb + kk * 68 + ((tx * 4) ^ sw));
            #pragma unroll
            for (int u = 0; u < 4; ++u)
                #pragma unroll
                for (int v = 0; v < 4; ++v)
                    acc[u][v] += av[u] * bv[v];
        }
    }
    __syncthreads();
    float* cbuf = xs[0];
    if (kh == 1) {
        #pragma unroll
        for (int u = 0; u < 4; ++u)
            *(fx4*)(cbuf + t256 * 16 + u * 4) = *(const fx4*)(&acc[u][0]);
    }
    __syncthreads();
    if (kh == 0) {
        float* tileT = wt[0];     // dead after compute: [f_local][j_local] pad 68
        #pragma unroll
        for (int u = 0; u < 4; ++u) {
            const fx4 o = *(const fx4*)(cbuf + t256 * 16 + u * 4);
            #pragma unroll
            for (int v = 0; v < 4; ++v) acc[u][v] += o[v];
        }
        const fx4 bv = *(const fx4*)(bias + bf * 64 + tx * 4);
        const fx4 w1v = *(const fx4*)(att_w + bf * 64 + tx * 4);
        const fx4 w2v = *(const fx4*)(att_w + 256 + bf * 64 + tx * 4);
        #pragma unroll
        for (int u = 0; u < 4; ++u) {
            const int i = bi * 64 + ty * 4 + u;
            fx4 r;
            float s1 = 0.f, s2 = 0.f;
            #pragma unroll
            for (int v = 0; v < 4; ++v) {
                r[v] = acc[u][v] + bv[v];
                s1 += r[v] * w1v[v];
                s2 += r[v] * w2v[v];
            }
            #pragma unroll
            for (int v = 0; v < 4; ++v)
                tileT[(tx * 4 + v) * 68 + ty * 4 + u] = r[v];
            #pragma unroll
            for (int d = 8; d > 0; d >>= 1) {
                s1 += __shfl_down(s1, d, 16);
                s2 += __shfl_down(s2, d, 16);
            }
            if (tx == 0) {
                a1p[bf * NN + i] = s1;
                a2p[bf * NN + i] = s2;
            }
        }
    }
    __syncthreads();
    {   // gt store: all 512 threads, 64 f-rows x 8 col-groups of 8 (LINEAR)
        const float* tileT = wt[0];
        const int fl = t >> 3, cb = t & 7;
        s8v v;
        #pragma unroll
        for (int lo = 0; lo < 8; ++lo)
            v[lo] = (short)f2bf(tileT[fl * 68 + cb * 8 + lo]);
        *(s8v*)(gt + (size_t)(bf * 64 + fl) * NN + bi * 64 + cb * 8) = v;
    }
}

// ---- k_prep: reduce a-partials, max/exp -> E1,E2, Sg=0, first-4096-edge scan ----
__global__ __launch_bounds__(1024) void k_prep(const float* __restrict__ a1p,
        const float* __restrict__ a2p, const int* __restrict__ adj,
        float* __restrict__ E1, float* __restrict__ E2,
        float* __restrict__ wraw, float* __restrict__ Sg) {
    __shared__ float E1s[NN];
    __shared__ float E2s[NN];
    __shared__ float red1[16], red2[16];
    __shared__ int wtot[16];
    __shared__ int base_s;
    const int t = threadIdx.x, lane = t & 63, wv = t >> 6;
    fx4 v1 = {0.f, 0.f, 0.f, 0.f}, v2 = {0.f, 0.f, 0.f, 0.f};
    #pragma unroll
    for (int bf = 0; bf < 4; ++bf) {
        v1 += *(const fx4*)(a1p + bf * NN + t * 4);
        v2 += *(const fx4*)(a2p + bf * NN + t * 4);
    }
    float m1 = fmaxf(fmaxf(v1[0], v1[1]), fmaxf(v1[2], v1[3]));
    float m2 = fmaxf(fmaxf(v2[0], v2[1]), fmaxf(v2[2], v2[3]));
    #pragma unroll
    for (int d = 32; d > 0; d >>= 1) {
        m1 = fmaxf(m1, __shfl_down(m1, d));
        m2 = fmaxf(m2, __shfl_down(m2, d));
    }
    if (lane == 0) { red1[wv] = m1; red2[wv] = m2; }
    __syncthreads();
    if (t == 0) {
        float mm1 = -1e30f, mm2 = -1e30f;
        for (int k = 0; k < 16; ++k) {
            mm1 = fmaxf(mm1, red1[k]);
            mm2 = fmaxf(mm2, red2[k]);
        }
        red1[0] = mm1; red2[0] = mm2;
        *Sg = 0.f;
        base_s = 0;
    }
    __syncthreads();
    const float M1 = red1[0], M2 = red2[0];
    fx4 e1v, e2v, z4 = {0.f, 0.f, 0.f, 0.f};
    #pragma unroll
    for (int j = 0; j < 4; ++j) {
        e1v[j] = expf(v1[j] - M1);
        e2v[j] = expf(v2[j] - M2);
    }
    *(fx4*)(E1s + t * 4) = e1v;
    *(fx4*)(E2s + t * 4) = e2v;
    *(fx4*)(E1 + t * 4) = e1v;
    *(fx4*)(E2 + t * 4) = e2v;
    *(fx4*)(wraw + t * 4) = z4;
    __syncthreads();
    for (int row = 0; row < NN; ++row) {
        const int base = base_s;           // uniform
        if (base >= NN) break;             // uniform break
        const int4 a = ((const int4*)(adj + (size_t)row * NN))[t];
        const int vj[4] = {a.x, a.y, a.z, a.w};
        int cnt = 0;
        #pragma unroll
        for (int j = 0; j < 4; ++j) cnt += (vj[j] == 1);
        int inc = cnt;
        #pragma unroll
        for (int d = 1; d < 64; d <<= 1) {
            const int y = __shfl_up(inc, d);
            if (lane >= d) inc += y;
        }
        if (lane == 63) wtot[wv] = inc;
        __syncthreads();                   // B1
        int wbase = 0, total = 0;
        #pragma unroll
        for (int w = 0; w < 16; ++w) {
            const int xw = wtot[w];
            total += xw;
            wbase += (w < wv) ? xw : 0;
        }
        if (t == 0) base_s = base + total;
        int r = base + wbase + inc - cnt;
        if (cnt && r < NN) {
            const float e1 = E1s[row];
            #pragma unroll
            for (int j = 0; j < 4; ++j) {
                if (vj[j] == 1) {
                    if (r < NN) wraw[r] = e1 * E2s[t * 4 + j];
                    ++r;
                }
            }
        }
        __syncthreads();                   // B2
    }
}

// -------- k_fused: part = (adj * bf16(wraw)) @ gt^T (bf16 MFMA, split-K) + S ----
// R4: true 2-phase pipeline. B-operand loaded straight to regs (wave-private
// f-rows; Gs LDS + global_load_lds DMA eliminated -> no vmcnt drain at the
// barrier), As double-buffered (1 barrier/step), adj prefetched 2 steps ahead
// (covers ~900cy HBM latency), wraw/E2/B one step ahead (L2-resident).
// LDS 18.5KB; VGPR ~210 -> 2 blocks/CU (8 waves).
__global__ __launch_bounds__(256, 2) void k_fused(const int* __restrict__ adj,
        const uint16_t* __restrict__ gt, const float* __restrict__ E1,
        const float* __restrict__ E2, const float* __restrict__ wraw,
        uint16_t* __restrict__ part, float* __restrict__ Sg, int krange) {
    __shared__ __align__(16) uint16_t As[2][64 * 72];
    __shared__ float sgred[4];
    const int ib = blockIdx.x, ks = blockIdx.y;
    const int t = threadIdx.x;
    const int wv = t >> 6, lane = t & 63;
    const int q = lane >> 4, m16 = lane & 15;
    const int i0 = ib * 64, k0 = ks * krange;
    const int ksteps = krange >> 6;                    // even (8/16/32/64)
    const int ar = t >> 4, ac4 = (t & 15) * 4;         // adj/As staging mapping
    fx4 acc[4][4];
    #pragma unroll
    for (int a = 0; a < 4; ++a)
        #pragma unroll
        for (int b2 = 0; b2 < 4; ++b2) acc[a][b2] = (fx4){0.f, 0.f, 0.f, 0.f};
    float sS = 0.f;
    float e1r[4];
    #pragma unroll
    for (int p = 0; p < 4; ++p) e1r[p] = E1[i0 + p * 16 + ar];
    // per-lane B row pointers (q*8 folded in): B[k][col] = gt[col][k]
    const uint16_t* rowp[4];
    #pragma unroll
    for (int ft = 0; ft < 4; ++ft)
        rowp[ft] = gt + (size_t)(wv * 64 + ft * 16 + m16) * NN + q * 8;

    // prologue: adj 2 ahead, wraw/E2/B 1 ahead
    int4 ra0[4], ra1[4];
    #pragma unroll
    for (int p = 0; p < 4; ++p)
        ra0[p] = *(const int4*)(adj + (size_t)(i0 + p * 16 + ar) * NN + k0 + ac4);
    #pragma unroll
    for (int p = 0; p < 4; ++p)
        ra1[p] = *(const int4*)(adj + (size_t)(i0 + p * 16 + ar) * NN + k0 + 64 + ac4);
    fx4 rwC = *(const fx4*)(wraw + k0 + ac4);
    fx4 reC = *(const fx4*)(E2 + k0 + ac4);
    s8v B0[4][2], B1[4][2];
    #pragma unroll
    for (int ft = 0; ft < 4; ++ft) {
        B0[ft][0] = *(const s8v*)(rowp[ft] + k0);
        B0[ft][1] = *(const s8v*)(rowp[ft] + k0 + 32);
    }

    auto step = [&](s8v (&Bc)[4][2], s8v (&Bn)[4][2], int4 (&Rc)[4], int stp) {
        const int cur = stp & 1;
        const int kk = k0 + stp * 64;
        // ---- stage As[cur]: adj gate x bf16(wraw) + exact S partial ----
        const uint16_t wb0 = f2bf(rwC[0]), wb1 = f2bf(rwC[1]);
        const uint16_t wb2 = f2bf(rwC[2]), wb3 = f2bf(rwC[3]);
        #pragma unroll
        for (int p = 0; p < 4; ++p) {
            uint2 wo;
            wo.x = (Rc[p].x == 1 ? (uint32_t)wb0 : 0u) |
                   ((Rc[p].y == 1 ? (uint32_t)wb1 : 0u) << 16);
            wo.y = (Rc[p].z == 1 ? (uint32_t)wb2 : 0u) |
                   ((Rc[p].w == 1 ? (uint32_t)wb3 : 0u) << 16);
            *(uint2*)(&As[cur][(p * 16 + ar) * 72 + ac4]) = wo;
            sS += e1r[p] * ((Rc[p].x == 1 ? reC[0] : 0.f) +
                            (Rc[p].y == 1 ? reC[1] : 0.f) +
                            (Rc[p].z == 1 ? reC[2] : 0.f) +
                            (Rc[p].w == 1 ? reC[3] : 0.f));
        }
        __syncthreads();   // As[cur] visible; other buffer free to stage next
        // ---- issue next loads post-barrier: hidden under MFMA below ----
        if (stp + 2 < ksteps) {
            #pragma unroll
            for (int p = 0; p < 4; ++p)
                Rc[p] = *(const int4*)(adj + (size_t)(i0 + p * 16 + ar) * NN +
                                       kk + 128 + ac4);
        }
        if (stp + 1 < ksteps) {
            rwC = *(const fx4*)(wraw + kk + 64 + ac4);
            reC = *(const fx4*)(E2 + kk + 64 + ac4);
            #pragma unroll
            for (int ft = 0; ft < 4; ++ft) {
                Bn[ft][0] = *(const s8v*)(rowp[ft] + kk + 64);
                Bn[ft][1] = *(const s8v*)(rowp[ft] + kk + 64 + 32);
            }
        }
        // ---- MFMA: A from LDS, B from regs ----
        s8v afr[4][2];
        #pragma unroll
        for (int it = 0; it < 4; ++it)
            #pragma unroll
            for (int khh = 0; khh < 2; ++khh)
                afr[it][khh] = *(const s8v*)(&As[cur][(it * 16 + m16) * 72 +
                                                      khh * 32 + q * 8]);
        #pragma unroll
        for (int ft = 0; ft < 4; ++ft)
            #pragma unroll
            for (int khh = 0; khh < 2; ++khh)
                #pragma unroll
                for (int it = 0; it < 4; ++it)
                    acc[it][ft] = __builtin_amdgcn_mfma_f32_16x16x32_bf16(
                        afr[it][khh], Bc[ft][khh], acc[it][ft], 0, 0, 0);
    };

    for (int stp = 0; stp < ksteps; stp += 2) {
        step(B0, B1, ra0, stp);
        step(B1, B0, ra1, stp + 1);
    }

    #pragma unroll
    for (int d = 32; d > 0; d >>= 1) sS += __shfl_down(sS, d);
    if (lane == 0) sgred[wv] = sS;
    __syncthreads();
    if (t == 0)
        atomicAdd(Sg, sgred[0] + sgred[1] + sgred[2] + sgred[3]);
    // bf16 partials; C/D layout: col=lane&15, row=(lane>>4)*4+reg
    uint16_t* dst = part + (size_t)ks * NN * FDIM;
    #pragma unroll
    for (int it = 0; it < 4; ++it) {
        #pragma unroll
        for (int ft = 0; ft < 4; ++ft) {
            const int f = wv * 64 + ft * 16 + m16;
            #pragma unroll
            for (int r = 0; r < 4; ++r) {
                const int i = i0 + it * 16 + q * 4 + r;
                dst[(size_t)i * FDIM + f] = f2bf(acc[it][ft][r]);
            }
        }
    }
}

// -------- k_out: out = relu(sum_k part_k) / S (bf16 partials, 8 f/thread) --------
__global__ __launch_bounds__(256) void k_out(const uint16_t* __restrict__ part,
        const float* __restrict__ Sg, float* __restrict__ out, int nsplit) {
    const size_t idx = ((size_t)blockIdx.x * 256 + threadIdx.x) * 8;
    const float inv = 1.0f / (*Sg);
    float s[8] = {};
    for (int k = 0; k < nsplit; ++k) {
        const s8v v = *(const s8v*)(part + (size_t)k * NN * FDIM + idx);
        #pragma unroll
        for (int j = 0; j < 8; ++j) {
            union { uint32_t u; float f; } cv;
            cv.u = ((uint32_t)(uint16_t)v[j]) << 16;
            s[j] += cv.f;
        }
    }
    fx4 r0, r1;
    #pragma unroll
    for (int j = 0; j < 4; ++j) {
        r0[j] = fmaxf(s[j], 0.f) * inv;
        r1[j] = fmaxf(s[4 + j], 0.f) * inv;
    }
    *(fx4*)(out + idx) = r0;
    *(fx4*)(out + idx + 4) = r1;
}

extern "C" void kernel_launch(void* const* d_in, const int* in_sizes, int n_in,
                              void* d_out, int out_size, void* d_ws, size_t ws_size,
                              hipStream_t stream) {
    const float* x     = (const float*)d_in[0];
    const int*   adj   = (const int*)d_in[1];
    const float* W     = (const float*)d_in[2];
    const float* bias  = (const float*)d_in[3];
    const float* att_w = (const float*)d_in[4];
    // att_b (d_in[5]) cancels exactly in the softmax — unused.
    float* out = (float*)d_out;
    char* ws = (char*)d_ws;
    uint16_t* gt   = (uint16_t*)(ws + 0);            // 2 MB: bf16(h) transposed
    float*    a1p  = (float*)(ws + 2097152);         // 64 KB (4 x 4096)
    float*    a2p  = (float*)(ws + 2162688);         // 64 KB
    float*    E1   = (float*)(ws + 2228224);         // 16 KB
    float*    E2   = (float*)(ws + 2244608);         // 16 KB
    float*    wraw = (float*)(ws + 2260992);         // 16 KB
    float*    Sg   = (float*)(ws + 2277376);         // 256 B
    uint16_t* part = (uint16_t*)(ws + 2277632);      // splitk x 2 MB (bf16)
    (void)in_sizes; (void)n_in; (void)out_size;

    const size_t avail = (ws_size > 2277632) ? (ws_size - 2277632) : 0;
    int splitk = 1;
    while (splitk < 8 &&
           (size_t)(splitk * 2) * NN * FDIM * sizeof(uint16_t) <= avail)
        splitk <<= 1;
    const int krange = NN / splitk;

    k_h    <<<dim3(64, 4), 512, 0, stream>>>(x, W, bias, att_w, gt, a1p, a2p);
    k_prep <<<dim3(1), 1024, 0, stream>>>(a1p, a2p, adj, E1, E2, wraw, Sg);
    k_fused<<<dim3(64, splitk), 256, 0, stream>>>(adj, gt, E1, E2, wraw, part, Sg, krange);
    k_out  <<<dim3(512), 256, 0, stream>>>(part, Sg, out, splitk);
}